// Round 5
// baseline (333.280 us; speedup 1.0000x reference)
//
#include <hip/hip_runtime.h>
#include <hip/hip_bf16.h>

#define BS 128
#define NR 3
#define CD 64
#define CG 3
#define HW 1024   // 32*32
#define K_IN 67   // CD + CG; k==67 is the folded-bias constant-1 column
#define P 64      // pixels per block

typedef __attribute__((ext_vector_type(4))) short bf16x4;
typedef __attribute__((ext_vector_type(8))) short bf16x8;
typedef __attribute__((ext_vector_type(4))) float f32x4;

static __device__ __forceinline__ short f2bf(float x) {
    union { __hip_bfloat16 b; short s; } c;
    c.b = __float2bfloat16(x);
    return c.s;
}
static __device__ __forceinline__ float bf2f(short s) {
    union { unsigned u; float f; } c;
    c.u = (unsigned)(unsigned short)s << 16;
    return c.f;
}

// byte offset of the 8B chunk holding channels 4*c2..4*c2+3 of pixel px, ref r.
// XOR swizzle spreads banks for both the px-major writes and the kq-major reads;
// applied identically on every access (both-sides-or-neither).
static __device__ __forceinline__ int xoff(int ref, int c2, int px) {
    return (((ref * 16 + c2) * 64 + px) * 8) ^ ((((c2 ^ (px >> 4)) & 3) << 5));
}

// ---------------------------------------------------------------------------
// prep: pack W1 (b1 folded at k=67) into MFMA-A fragment order, bf16.
// w1f[((mt*3 + t)*64 + lane)*8 + j]: A row = mt*16+(lane&15),
// k = t*32 + (lane>>4)*8 + j.  49 KB into d_ws.  (unchanged - verified)
// ---------------------------------------------------------------------------
__global__ __launch_bounds__(256) void prep_kernel(
    const float* __restrict__ W1, const float* __restrict__ b1,
    short* __restrict__ w1f)
{
    const int fid  = blockIdx.x * 256 + threadIdx.x;  // 0..3071
    const int mt   = fid / 192;
    const int rem  = fid % 192;
    const int t    = rem >> 6;
    const int lane = rem & 63;
    const int row  = mt * 16 + (lane & 15);
    const int k0   = t * 32 + (lane >> 4) * 8;
    bf16x8 v;
#pragma unroll
    for (int j = 0; j < 8; ++j) {
        const int k = k0 + j;
        float val = 0.f;
        if (k < K_IN)       val = W1[row * K_IN + k];
        else if (k == K_IN) val = b1[row];
        v[j] = f2bf(val);
    }
    *(bf16x8*)&w1f[(size_t)fid * 8] = v;
}

// ---------------------------------------------------------------------------
// fused kernel.  LDS x: swizzled 8B chunks (see xoff).  k=64..95 shared
// gt-page (g0,g1,g2,1) + zero-page.  3 barriers total.
// ---------------------------------------------------------------------------
__global__ __launch_bounds__(256, 5) void fused_kernel(
    const float* __restrict__ data, const float* __restrict__ gt,
    const short* __restrict__ w1f, const float* __restrict__ W3,
    const float* __restrict__ b3, float* __restrict__ out)
{
    __shared__ __align__(16) char xls[NR * 16 * P * 8];  // 24576 B
    __shared__ short gtp[P * 4];            // 512 B: (g0,g1,g2,1) per px
    __shared__ short zp[P * 4];             // 512 B zeros
    __shared__ float p_lds[4][NR * P];      // 3 KB
    __shared__ float s_lds[NR][P];          // 768 B

    const int tid  = threadIdx.x;
    const int lane = tid & 63;
    const int wave = tid >> 6;
    const int b    = blockIdx.x >> 4;          // 0..127
    const int pt0  = (blockIdx.x & 15) * P;    // pixel tile base
    const int col  = lane & 15, kq = lane >> 4;

    // ---- zero page + gt page ----
    if (tid < P) *(bf16x4*)&zp[tid * 4] = (bf16x4){0, 0, 0, 0};
    {
        const int c = tid >> 6, px = tid & 63;
        if (c < CG) gtp[px * 4 + c] = f2bf(gt[((size_t)b * CG + c) * HW + pt0 + px]);
        else        gtp[px * 4 + 3] = (short)0x3F80;   // 1.0 bf16 (bias column)
    }

    // ---- data staging: unit = (ref,c2,px) -> 4 coalesced dword loads,
    //      pack, one swizzled ds_write_b64.  3 passes of 4 units. ----
    bf16x8 afrag[4][3];
    float  w3v[4][4];
#pragma unroll
    for (int pass = 0; pass < 3; ++pass) {
        float ld[4][4];
#pragma unroll
        for (int u = 0; u < 4; ++u) {
            const int uid = (pass * 4 + u) * 256 + tid;
            const int ref = uid >> 10, c2 = (uid >> 6) & 15, px = uid & 63;
            const float* dp = data + ((size_t)(b * NR + ref) * CD + 4 * c2) * HW + pt0 + px;
#pragma unroll
            for (int i = 0; i < 4; ++i) ld[u][i] = dp[(size_t)i * HW];
        }
        if (pass == 0) {   // overlap A-frag loads with staging latency
#pragma unroll
            for (int i = 0; i < 4; ++i)
#pragma unroll
                for (int t = 0; t < 3; ++t)
                    afrag[i][t] = *(const bf16x8*)&w1f[(((size_t)(wave * 4 + i) * 3 + t) * 64 + lane) * 8];
        }
        if (pass == 1) {
#pragma unroll
            for (int i = 0; i < 4; ++i)
#pragma unroll
                for (int r = 0; r < 4; ++r)
                    w3v[i][r] = W3[wave * 64 + i * 16 + kq * 4 + r];
        }
#pragma unroll
        for (int u = 0; u < 4; ++u) {
            const int uid = (pass * 4 + u) * 256 + tid;
            const int ref = uid >> 10, c2 = (uid >> 6) & 15, px = uid & 63;
            bf16x4 v;
#pragma unroll
            for (int i = 0; i < 4; ++i) v[i] = f2bf(ld[u][i]);
            *(bf16x4*)&xls[xoff(ref, c2, px)] = v;
        }
    }

    __syncthreads();

    // ---- MFMA: 12 n-tiles (3 refs x 4 pixel sub-tiles of 16) ----
#pragma unroll
    for (int nt = 0; nt < NR * 4; ++nt) {
        const int ref = nt >> 2, pn0 = (nt & 3) * 16;
        const int px  = pn0 + col;
        bf16x8 bfrag[3];
#pragma unroll
        for (int t = 0; t < 2; ++t) {
            const int c2 = t * 8 + kq * 2;
            const bf16x4 lo = *(const bf16x4*)&xls[xoff(ref, c2, px)];
            const bf16x4 hi = *(const bf16x4*)&xls[xoff(ref, c2 + 1, px)];
            bfrag[t] = __builtin_shufflevector(lo, hi, 0, 1, 2, 3, 4, 5, 6, 7);
        }
        {   // k = 64..95: shared gt/zero pages (broadcast reads are free)
            const bf16x4 lo = (kq == 0) ? *(const bf16x4*)&gtp[px * 4]
                                        : *(const bf16x4*)&zp[px * 4];
            const bf16x4 hi = *(const bf16x4*)&zp[px * 4];
            bfrag[2] = __builtin_shufflevector(lo, hi, 0, 1, 2, 3, 4, 5, 6, 7);
        }

        f32x4 acc[4];
#pragma unroll
        for (int i = 0; i < 4; ++i) acc[i] = (f32x4){0.f, 0.f, 0.f, 0.f};
        __builtin_amdgcn_s_setprio(1);
#pragma unroll
        for (int t = 0; t < 3; ++t)
#pragma unroll
            for (int i = 0; i < 4; ++i)
                acc[i] = __builtin_amdgcn_mfma_f32_16x16x32_bf16(
                    afrag[i][t], bfrag[t], acc[i], 0, 0, 0);
        __builtin_amdgcn_s_setprio(0);

        float partial = 0.f;
#pragma unroll
        for (int i = 0; i < 4; ++i)
#pragma unroll
            for (int r = 0; r < 4; ++r)
                partial += w3v[i][r] * fmaxf(acc[i][r], 0.f);
        partial += __shfl_xor(partial, 16);
        partial += __shfl_xor(partial, 32);
        if (lane < 16) p_lds[wave][ref * P + pn0 + lane] = partial;
    }
    __syncthreads();

    // ---- cross-wave sum + bias -> sigmoid ----
    if (tid < NR * P) {
        const float t = p_lds[0][tid] + p_lds[1][tid] + p_lds[2][tid]
                      + p_lds[3][tid] + b3[0];
        s_lds[tid >> 6][tid & 63] = 1.f / (1.f + __expf(-t));
    }
    __syncthreads();

    // ---- z = sum_ref w*d (w recomputed from s_lds; no extra barrier),
    //      plus w global write from the v==0 units. ----
    float* wout = out + (size_t)BS * CD * HW;
#pragma unroll
    for (int v = 0; v < 4; ++v) {
        const int vid = v * 256 + tid;
        const int c2 = vid >> 6, px = vid & 63;
        const float s0 = s_lds[0][px], s1 = s_lds[1][px], s2 = s_lds[2][px];
        const float inv = 1.f / (s0 + s1 + s2);
        if (v == 0 && c2 < NR) {
            const float sv = (c2 == 0) ? s0 : (c2 == 1) ? s1 : s2;
            wout[((size_t)b * NR + c2) * HW + pt0 + px] = sv * inv;
        }
        float z0 = 0.f, z1 = 0.f, z2 = 0.f, z3 = 0.f;
#pragma unroll
        for (int ref = 0; ref < NR; ++ref) {
            const float w = ((ref == 0) ? s0 : (ref == 1) ? s1 : s2) * inv;
            const bf16x4 d = *(const bf16x4*)&xls[xoff(ref, c2, px)];
            z0 += w * bf2f(d[0]);
            z1 += w * bf2f(d[1]);
            z2 += w * bf2f(d[2]);
            z3 += w * bf2f(d[3]);
        }
        float* zout = out + ((size_t)b * CD + 4 * c2) * HW + pt0 + px;
        zout[0 * HW] = z0;
        zout[1 * HW] = z1;
        zout[2 * HW] = z2;
        zout[3 * HW] = z3;
    }
}

extern "C" void kernel_launch(void* const* d_in, const int* in_sizes, int n_in,
                              void* d_out, int out_size, void* d_ws, size_t ws_size,
                              hipStream_t stream)
{
    const float* data = (const float*)d_in[0];
    const float* gt   = (const float*)d_in[1];
    const float* W1   = (const float*)d_in[2];
    const float* b1   = (const float*)d_in[3];
    const float* W3   = (const float*)d_in[4];
    const float* b3   = (const float*)d_in[5];
    float* out  = (float*)d_out;
    short* w1f  = (short*)d_ws;   // 3072*8 bf16 = 49 KB fragment-ordered W1

    prep_kernel<<<12, 256, 0, stream>>>(W1, b1, w1f);
    fused_kernel<<<BS * (HW / P), 256, 0, stream>>>(data, gt, w1f, W3, b3, out);
}

// Round 7
// 175.354 us; speedup vs baseline: 1.9006x; 1.9006x over previous
//
#include <hip/hip_runtime.h>
#include <hip/hip_bf16.h>

#define BS 128
#define NR 3
#define CD 64
#define CG 3
#define HW 1024   // 32*32
#define K_IN 67   // CD + CG; k==67 is the folded-bias constant-1 column
#define P 64      // pixels per block

typedef __attribute__((ext_vector_type(4))) short bf16x4;
typedef __attribute__((ext_vector_type(8))) short bf16x8;
typedef __attribute__((ext_vector_type(4))) float f32x4;

static __device__ __forceinline__ short f2bf(float x) {
    union { __hip_bfloat16 b; short s; } c;
    c.b = __float2bfloat16(x);
    return c.s;
}
static __device__ __forceinline__ float bf2f(short s) {
    union { unsigned u; float f; } c;
    c.u = (unsigned)(unsigned short)s << 16;
    return c.f;
}

// Byte offset of the 8B chunk holding channels 4*c2..4*c2+3 of pixel px, ref.
// XOR swizzle keyed on (c2>>1, px>>4): the four kq read-groups (c2 stride 2)
// and the four aliasing px-groups each land in distinct 32B windows -> <=2-way
// on ds_read_b64 / b16 scatter / z reads.  Same involution at every site.
static __device__ __forceinline__ int xoff(int ref, int c2, int px) {
    return (((ref * 16 + c2) * 64 + px) * 8) ^ (((((c2 >> 1) ^ (px >> 4)) & 3)) << 5);
}

// ---------------------------------------------------------------------------
// prep: pack W1 (b1 folded at k=67) into MFMA-A fragment order, bf16.
// w1f[((mt*3 + t)*64 + lane)*8 + j]: A row = mt*16+(lane&15),
// k = t*32 + (lane>>4)*8 + j.  49 KB into d_ws.  (unchanged - verified)
// ---------------------------------------------------------------------------
__global__ __launch_bounds__(256) void prep_kernel(
    const float* __restrict__ W1, const float* __restrict__ b1,
    short* __restrict__ w1f)
{
    const int fid  = blockIdx.x * 256 + threadIdx.x;  // 0..3071
    const int mt   = fid / 192;
    const int rem  = fid % 192;
    const int t    = rem >> 6;
    const int lane = rem & 63;
    const int row  = mt * 16 + (lane & 15);
    const int k0   = t * 32 + (lane >> 4) * 8;
    bf16x8 v;
#pragma unroll
    for (int j = 0; j < 8; ++j) {
        const int k = k0 + j;
        float val = 0.f;
        if (k < K_IN)       val = W1[row * K_IN + k];
        else if (k == K_IN) val = b1[row];
        v[j] = f2bf(val);
    }
    *(bf16x8*)&w1f[(size_t)fid * 8] = v;
}

// ---------------------------------------------------------------------------
// fused kernel (R4 structure + xls swizzle, w_lds removed).
// ---------------------------------------------------------------------------
__global__ __launch_bounds__(256, 4) void fused_kernel(
    const float* __restrict__ data, const float* __restrict__ gt,
    const short* __restrict__ w1f, const float* __restrict__ W3,
    const float* __restrict__ b3, float* __restrict__ out)
{
    __shared__ __align__(16) char xls[NR * 16 * P * 8];  // 24576 B
    __shared__ __align__(16) short gtp[P * 4];           // 512 B (g0,g1,g2,1)
    __shared__ __align__(16) short zp[P * 4];            // 512 B zeros
    __shared__ __align__(16) float p_lds[4][NR * P];     // 3 KB
    __shared__ __align__(16) float s_lds[NR][P];         // 768 B

    const int tid  = threadIdx.x;
    const int lane = tid & 63;
    const int wave = tid >> 6;
    const int b    = blockIdx.x >> 4;          // 0..127
    const int pt0  = (blockIdx.x & 15) * P;    // pixel tile base
    const int col  = lane & 15, kq = lane >> 4;

    // ---- A-frags + W3 (issue early; overlap with staging) ----
    bf16x8 afrag[4][3];
#pragma unroll
    for (int i = 0; i < 4; ++i)
#pragma unroll
        for (int t = 0; t < 3; ++t)
            afrag[i][t] = *(const bf16x8*)&w1f[(((size_t)(wave * 4 + i) * 3 + t) * 64 + lane) * 8];
    float w3v[4][4];
#pragma unroll
    for (int i = 0; i < 4; ++i)
#pragma unroll
        for (int r = 0; r < 4; ++r)
            w3v[i][r] = W3[wave * 64 + i * 16 + kq * 4 + r];

    // ---- zero page + gt page ----
    if (tid < P) *(bf16x4*)&zp[tid * 4] = (bf16x4){0, 0, 0, 0};
    {
        const int c = tid >> 6, px = tid & 63;
        if (c < CG) gtp[px * 4 + c] = f2bf(gt[((size_t)b * CG + c) * HW + pt0 + px]);
        else        gtp[px * 4 + 3] = (short)0x3F80;   // 1.0 bf16 (bias column)
    }

    // ---- data staging: 12 float4 loads/thread, swizzled bf16 scatter ----
#pragma unroll
    for (int half = 0; half < 2; ++half) {
        float4 ld[6];
#pragma unroll
        for (int u = 0; u < 6; ++u) {
            const int q = (half * 6 + u) * 256 + tid;
            const int ref = q >> 10, ch = (q >> 4) & 63, p4 = q & 15;
            ld[u] = *(const float4*)(data + ((size_t)(b * NR + ref) * CD + ch) * HW + pt0 + 4 * p4);
        }
#pragma unroll
        for (int u = 0; u < 6; ++u) {
            const int q = (half * 6 + u) * 256 + tid;
            const int ref = q >> 10, ch = (q >> 4) & 63, p4 = q & 15;
            short* xp = (short*)&xls[xoff(ref, ch >> 2, 4 * p4)] + (ch & 3);
            xp[0]  = f2bf(ld[u].x);
            xp[4]  = f2bf(ld[u].y);
            xp[8]  = f2bf(ld[u].z);
            xp[12] = f2bf(ld[u].w);
        }
    }

    __syncthreads();

    // ---- MFMA: 12 n-tiles (3 refs x 4 pixel sub-tiles of 16) ----
#pragma unroll
    for (int nt = 0; nt < NR * 4; ++nt) {
        const int ref = nt >> 2, pn0 = (nt & 3) * 16;
        const int px  = pn0 + col;
        bf16x8 bfrag[3];
#pragma unroll
        for (int t = 0; t < 2; ++t) {
            const int c2 = t * 8 + kq * 2;
            const bf16x4 lo = *(const bf16x4*)&xls[xoff(ref, c2, px)];
            const bf16x4 hi = *(const bf16x4*)&xls[xoff(ref, c2 + 1, px)];
            bfrag[t] = __builtin_shufflevector(lo, hi, 0, 1, 2, 3, 4, 5, 6, 7);
        }
        {   // k = 64..95: shared gt/zero pages (same-address reads broadcast)
            const bf16x4 lo = (kq == 0) ? *(const bf16x4*)&gtp[px * 4]
                                        : *(const bf16x4*)&zp[px * 4];
            const bf16x4 hi = *(const bf16x4*)&zp[px * 4];
            bfrag[2] = __builtin_shufflevector(lo, hi, 0, 1, 2, 3, 4, 5, 6, 7);
        }

        f32x4 acc[4];
#pragma unroll
        for (int i = 0; i < 4; ++i) acc[i] = (f32x4){0.f, 0.f, 0.f, 0.f};
#pragma unroll
        for (int t = 0; t < 3; ++t)
#pragma unroll
            for (int i = 0; i < 4; ++i)
                acc[i] = __builtin_amdgcn_mfma_f32_16x16x32_bf16(
                    afrag[i][t], bfrag[t], acc[i], 0, 0, 0);

        float partial = 0.f;
#pragma unroll
        for (int i = 0; i < 4; ++i)
#pragma unroll
            for (int r = 0; r < 4; ++r)
                partial += w3v[i][r] * fmaxf(acc[i][r], 0.f);
        partial += __shfl_xor(partial, 16);
        partial += __shfl_xor(partial, 32);
        if (lane < 16) p_lds[wave][ref * P + pn0 + lane] = partial;
    }
    __syncthreads();

    // ---- cross-wave sum + bias -> sigmoid ----
    if (tid < NR * P) {
        const float t = p_lds[0][tid] + p_lds[1][tid] + p_lds[2][tid]
                      + p_lds[3][tid] + b3[0];
        s_lds[tid >> 6][tid & 63] = 1.f / (1.f + __expf(-t));
    }
    __syncthreads();

    // ---- w global write (192 threads, coalesced) ----
    float* wout = out + (size_t)BS * CD * HW;
    if (tid < NR * P) {
        const int ref = tid >> 6, px = tid & 63;
        const float inv = 1.f / (s_lds[0][px] + s_lds[1][px] + s_lds[2][px]);
        wout[((size_t)b * NR + ref) * HW + pt0 + px] = s_lds[ref][px] * inv;
    }

    // ---- z = sum_ref w*d (w recomputed from s_lds; float4 stores) ----
#pragma unroll
    for (int u = 0; u < 4; ++u) {
        const int q = u * 256 + tid;
        const int ch = q >> 4, p4 = q & 15;
        const float4 S0 = *(const float4*)&s_lds[0][4 * p4];
        const float4 S1 = *(const float4*)&s_lds[1][4 * p4];
        const float4 S2 = *(const float4*)&s_lds[2][4 * p4];
        float4 inv;
        inv.x = 1.f / (S0.x + S1.x + S2.x);
        inv.y = 1.f / (S0.y + S1.y + S2.y);
        inv.z = 1.f / (S0.z + S1.z + S2.z);
        inv.w = 1.f / (S0.w + S1.w + S2.w);
        float zx = 0.f, zy = 0.f, zz = 0.f, zw = 0.f;
#pragma unroll
        for (int ref = 0; ref < NR; ++ref) {
            const float4 S = (ref == 0) ? S0 : (ref == 1) ? S1 : S2;
            const short* xp = (const short*)&xls[xoff(ref, ch >> 2, 4 * p4)] + (ch & 3);
            zx += S.x * inv.x * bf2f(xp[0]);
            zy += S.y * inv.y * bf2f(xp[4]);
            zz += S.z * inv.z * bf2f(xp[8]);
            zw += S.w * inv.w * bf2f(xp[12]);
        }
        const float4 zv = {zx, zy, zz, zw};
        *(float4*)(out + ((size_t)b * CD + ch) * HW + pt0 + 4 * p4) = zv;
    }
}

extern "C" void kernel_launch(void* const* d_in, const int* in_sizes, int n_in,
                              void* d_out, int out_size, void* d_ws, size_t ws_size,
                              hipStream_t stream)
{
    const float* data = (const float*)d_in[0];
    const float* gt   = (const float*)d_in[1];
    const float* W1   = (const float*)d_in[2];
    const float* b1   = (const float*)d_in[3];
    const float* W3   = (const float*)d_in[4];
    const float* b3   = (const float*)d_in[5];
    float* out  = (float*)d_out;
    short* w1f  = (short*)d_ws;   // 3072*8 bf16 = 49 KB fragment-ordered W1

    prep_kernel<<<12, 256, 0, stream>>>(W1, b1, w1f);
    fused_kernel<<<BS * (HW / P), 256, 0, stream>>>(data, gt, w1f, W3, b3, out);
}